// Round 2
// baseline (159.541 us; speedup 1.0000x reference)
//
#include <hip/hip_runtime.h>
#include <math.h>

// Problem constants (from reference): B=64, J=17, H=W=96 -> HW=9216, TOPK=8
#define NB 64
#define NJ 17
#define HW 9216
#define NBJ (NB * NJ)
#define TOPK_K 8
#define NSEG 3
#define SEG_F4 (HW / 4 / NSEG)   // 768 float4 per segment

// Pass 1: 3 blocks per (b,j) slice (one per segment of 3072 px).
// Each thread loads 3 float4 per tensor (9 loads in flight) -> latency hidden.
__global__ __launch_bounds__(256) void pass1_kernel(
    const float* __restrict__ s,
    const float* __restrict__ t,
    const float* __restrict__ g,
    const float* __restrict__ w,
    float* __restrict__ ws)
{
    const int bj  = blockIdx.x / NSEG;
    const int seg = blockIdx.x % NSEG;
    const size_t base4 = (size_t)bj * (HW / 4) + (size_t)seg * SEG_F4;
    const float4* __restrict__ s4 = (const float4*)s + base4;
    const float4* __restrict__ t4 = (const float4*)t + base4;
    const float4* __restrict__ g4 = (const float4*)g + base4;
    const float wv = w[bj];  // target_weight[b, j, 0]

    const int i0 = threadIdx.x;
    const int i1 = threadIdx.x + 256;
    const int i2 = threadIdx.x + 512;

    // Issue all 9 loads before any use.
    float4 a0 = s4[i0], a1 = s4[i1], a2 = s4[i2];
    float4 b0 = t4[i0], b1 = t4[i1], b2 = t4[i2];
    float4 c0 = g4[i0], c1 = g4[i1], c2 = g4[i2];

    float ssg = 0.f, sst = 0.f, mg = -INFINITY;

    #define ACCUM(av, bv, cv)                                              \
        {                                                                  \
            float sw = (av) * wv, tw = (bv) * wv, gw = (cv) * wv;          \
            float d1 = sw - gw, d2 = sw - tw;                              \
            ssg += d1 * d1; sst += d2 * d2; mg = fmaxf(mg, (cv));          \
        }

    ACCUM(a0.x, b0.x, c0.x) ACCUM(a0.y, b0.y, c0.y)
    ACCUM(a0.z, b0.z, c0.z) ACCUM(a0.w, b0.w, c0.w)
    ACCUM(a1.x, b1.x, c1.x) ACCUM(a1.y, b1.y, c1.y)
    ACCUM(a1.z, b1.z, c1.z) ACCUM(a1.w, b1.w, c1.w)
    ACCUM(a2.x, b2.x, c2.x) ACCUM(a2.y, b2.y, c2.y)
    ACCUM(a2.z, b2.z, c2.z) ACCUM(a2.w, b2.w, c2.w)
    #undef ACCUM

    // wave64 butterfly reduction
    #pragma unroll
    for (int off = 32; off > 0; off >>= 1) {
        ssg += __shfl_down(ssg, off);
        sst += __shfl_down(sst, off);
        mg = fmaxf(mg, __shfl_down(mg, off));
    }

    __shared__ float sh_sg[4], sh_st[4], sh_mg[4];
    const int wave = threadIdx.x >> 6;
    const int lane = threadIdx.x & 63;
    if (lane == 0) { sh_sg[wave] = ssg; sh_st[wave] = sst; sh_mg[wave] = mg; }
    __syncthreads();
    if (threadIdx.x == 0) {
        float a = sh_sg[0] + sh_sg[1] + sh_sg[2] + sh_sg[3];
        float b = sh_st[0] + sh_st[1] + sh_st[2] + sh_st[3];
        float m = fmaxf(fmaxf(sh_mg[0], sh_mg[1]), fmaxf(sh_mg[2], sh_mg[3]));
        // layout: [metric][seg][bj]
        ws[(0 * NSEG + seg) * NBJ + bj] = a;
        ws[(1 * NSEG + seg) * NBJ + bj] = b;
        ws[(2 * NSEG + seg) * NBJ + bj] = m;
    }
}

// Pass 2: single block of 64 threads (one wave). Finish all reductions.
__global__ __launch_bounds__(64) void pass2_kernel(
    const float* __restrict__ ws,
    const int* __restrict__ enj_p,
    float* __restrict__ out)
{
    __shared__ float cond_sh[NJ];  // 1.0 if cond[j] else 0.0
    __shared__ float msum_sh[NJ];  // per-joint mse contribution

    const int tid = threadIdx.x;

    if (tid < NJ) {
        float ssg = 0.f, sst = 0.f, mg = -INFINITY;
        for (int b = 0; b < NB; ++b) {
            #pragma unroll
            for (int seg = 0; seg < NSEG; ++seg) {
                ssg += ws[(0 * NSEG + seg) * NBJ + b * NJ + tid];
                sst += ws[(1 * NSEG + seg) * NBJ + b * NJ + tid];
                mg = fmaxf(mg, ws[(2 * NSEG + seg) * NBJ + b * NJ + tid]);
            }
        }
        const bool cond = (mg == 1.0f);
        cond_sh[tid] = cond ? 1.f : 0.f;
        const float inv_bhw = 1.f / (float)(NB * HW);
        const float m_sg = ssg * inv_bhw;
        const float m_st = sst * inv_bhw;
        msum_sh[tid] = cond ? m_sg : (m_sg + m_st);
    }
    __syncthreads();

    // per-sample loss_mat row + top-k (one thread per b; 64 threads = 64 b's)
    float lm[NJ];
    const float inv_hw = 1.f / (float)HW;
    #pragma unroll
    for (int j = 0; j < NJ; ++j) {
        float ssg = 0.f, sst = 0.f;
        #pragma unroll
        for (int seg = 0; seg < NSEG; ++seg) {
            ssg += ws[(0 * NSEG + seg) * NBJ + tid * NJ + j];
            sst += ws[(1 * NSEG + seg) * NBJ + tid * NJ + j];
        }
        const float v = (cond_sh[j] != 0.f) ? ssg : (ssg + sst);
        lm[j] = 0.5f * v * inv_hw;
    }
    float tk = 0.f;
    for (int k = 0; k < TOPK_K; ++k) {
        int mi = 0;
        float mv = lm[0];
        #pragma unroll
        for (int j = 1; j < NJ; ++j) {
            if (lm[j] > mv) { mv = lm[j]; mi = j; }
        }
        tk += mv;
        #pragma unroll
        for (int j = 0; j < NJ; ++j) {
            if (j == mi) lm[j] = -INFINITY;
        }
    }
    // reduce tk over the 64 samples (single wave)
    #pragma unroll
    for (int off = 32; off > 0; off >>= 1) tk += __shfl_down(tk, off);

    if (tid == 0) {
        const float ohkm = tk / (float)(TOPK_K * NB);
        float mse = 0.f;
        for (int j = 0; j < NJ; ++j) mse += msum_sh[j];
        const float enj = (float)(*enj_p);
        out[0] = ohkm;
        out[1] = mse / enj;
        out[2] = ohkm + mse;
    }
}

extern "C" void kernel_launch(void* const* d_in, const int* in_sizes, int n_in,
                              void* d_out, int out_size, void* d_ws, size_t ws_size,
                              hipStream_t stream) {
    const float* output_s = (const float*)d_in[0];
    const float* output_t = (const float*)d_in[1];
    const float* target   = (const float*)d_in[2];
    const float* tweight  = (const float*)d_in[3];
    const int*   enj      = (const int*)d_in[4];
    float* out = (float*)d_out;
    float* ws  = (float*)d_ws;  // 9 * NBJ floats

    pass1_kernel<<<NBJ * NSEG, 256, 0, stream>>>(output_s, output_t, target, tweight, ws);
    pass2_kernel<<<1, 64, 0, stream>>>(ws, enj, out);
}

// Round 3
// 149.097 us; speedup vs baseline: 1.0701x; 1.0701x over previous
//
#include <hip/hip_runtime.h>
#include <math.h>

// Problem constants (from reference): B=64, J=17, H=W=96 -> HW=9216, TOPK=8
#define NB 64
#define NJ 17
#define HW 9216
#define NBJ (NB * NJ)
#define TOPK_K 8

// Pass 1: one block per (b,j) slice; 256 threads; whole slice fully unrolled:
// 9 float4 per tensor per thread, all 27 loads independent (MLP-maximized).
__global__ __launch_bounds__(256) void pass1_kernel(
    const float* __restrict__ s,
    const float* __restrict__ t,
    const float* __restrict__ g,
    const float* __restrict__ w,
    float* __restrict__ ws)
{
    const int bj = blockIdx.x;
    const size_t base4 = (size_t)bj * (HW / 4);
    const float4* __restrict__ s4 = (const float4*)s + base4;
    const float4* __restrict__ t4 = (const float4*)t + base4;
    const float4* __restrict__ g4 = (const float4*)g + base4;
    const float wv = w[bj];  // target_weight[b, j, 0]

    // Issue all 27 loads up front; no loop, no serialization.
    float4 a[9], b[9], c[9];
    #pragma unroll
    for (int k = 0; k < 9; ++k) a[k] = s4[threadIdx.x + k * 256];
    #pragma unroll
    for (int k = 0; k < 9; ++k) b[k] = t4[threadIdx.x + k * 256];
    #pragma unroll
    for (int k = 0; k < 9; ++k) c[k] = g4[threadIdx.x + k * 256];

    float ssg = 0.f, sst = 0.f, mg = -INFINITY;

    #define ACCUM(av, bv, cv)                                              \
        {                                                                  \
            float sw = (av) * wv, tw = (bv) * wv, gw = (cv) * wv;          \
            float d1 = sw - gw, d2 = sw - tw;                              \
            ssg += d1 * d1; sst += d2 * d2; mg = fmaxf(mg, (cv));          \
        }

    #pragma unroll
    for (int k = 0; k < 9; ++k) {
        ACCUM(a[k].x, b[k].x, c[k].x)
        ACCUM(a[k].y, b[k].y, c[k].y)
        ACCUM(a[k].z, b[k].z, c[k].z)
        ACCUM(a[k].w, b[k].w, c[k].w)
    }
    #undef ACCUM

    // wave64 butterfly reduction
    #pragma unroll
    for (int off = 32; off > 0; off >>= 1) {
        ssg += __shfl_down(ssg, off);
        sst += __shfl_down(sst, off);
        mg = fmaxf(mg, __shfl_down(mg, off));
    }

    __shared__ float sh_sg[4], sh_st[4], sh_mg[4];
    const int wave = threadIdx.x >> 6;
    const int lane = threadIdx.x & 63;
    if (lane == 0) { sh_sg[wave] = ssg; sh_st[wave] = sst; sh_mg[wave] = mg; }
    __syncthreads();
    if (threadIdx.x == 0) {
        float sa = sh_sg[0] + sh_sg[1] + sh_sg[2] + sh_sg[3];
        float sb = sh_st[0] + sh_st[1] + sh_st[2] + sh_st[3];
        float m = fmaxf(fmaxf(sh_mg[0], sh_mg[1]), fmaxf(sh_mg[2], sh_mg[3]));
        ws[bj] = sa;
        ws[NBJ + bj] = sb;
        ws[2 * NBJ + bj] = m;
    }
}

// Pass 2: single block of 64 threads (one wave). Finish all reductions.
__global__ __launch_bounds__(64) void pass2_kernel(
    const float* __restrict__ ws,
    const int* __restrict__ enj_p,
    float* __restrict__ out)
{
    __shared__ float cond_sh[NJ];  // 1.0 if cond[j] else 0.0
    __shared__ float msum_sh[NJ];  // per-joint mse contribution

    const int tid = threadIdx.x;

    if (tid < NJ) {
        float ssg = 0.f, sst = 0.f, mg = -INFINITY;
        for (int b = 0; b < NB; ++b) {
            ssg += ws[b * NJ + tid];
            sst += ws[NBJ + b * NJ + tid];
            mg = fmaxf(mg, ws[2 * NBJ + b * NJ + tid]);
        }
        const bool cond = (mg == 1.0f);
        cond_sh[tid] = cond ? 1.f : 0.f;
        const float inv_bhw = 1.f / (float)(NB * HW);
        const float m_sg = ssg * inv_bhw;
        const float m_st = sst * inv_bhw;
        msum_sh[tid] = cond ? m_sg : (m_sg + m_st);
    }
    __syncthreads();

    // per-sample loss_mat row + top-k (one thread per b; 64 threads = 64 b's)
    float lm[NJ];
    const float inv_hw = 1.f / (float)HW;
    #pragma unroll
    for (int j = 0; j < NJ; ++j) {
        const float ssg = ws[tid * NJ + j];
        const float sst = ws[NBJ + tid * NJ + j];
        const float v = (cond_sh[j] != 0.f) ? ssg : (ssg + sst);
        lm[j] = 0.5f * v * inv_hw;
    }
    float tk = 0.f;
    for (int k = 0; k < TOPK_K; ++k) {
        int mi = 0;
        float mv = lm[0];
        #pragma unroll
        for (int j = 1; j < NJ; ++j) {
            if (lm[j] > mv) { mv = lm[j]; mi = j; }
        }
        tk += mv;
        #pragma unroll
        for (int j = 0; j < NJ; ++j) {
            if (j == mi) lm[j] = -INFINITY;
        }
    }
    // reduce tk over the 64 samples (single wave)
    #pragma unroll
    for (int off = 32; off > 0; off >>= 1) tk += __shfl_down(tk, off);

    if (tid == 0) {
        const float ohkm = tk / (float)(TOPK_K * NB);
        float mse = 0.f;
        for (int j = 0; j < NJ; ++j) mse += msum_sh[j];
        const float enj = (float)(*enj_p);
        out[0] = ohkm;
        out[1] = mse / enj;
        out[2] = ohkm + mse;
    }
}

extern "C" void kernel_launch(void* const* d_in, const int* in_sizes, int n_in,
                              void* d_out, int out_size, void* d_ws, size_t ws_size,
                              hipStream_t stream) {
    const float* output_s = (const float*)d_in[0];
    const float* output_t = (const float*)d_in[1];
    const float* target   = (const float*)d_in[2];
    const float* tweight  = (const float*)d_in[3];
    const int*   enj      = (const int*)d_in[4];
    float* out = (float*)d_out;
    float* ws  = (float*)d_ws;  // 3 * NBJ floats

    pass1_kernel<<<NBJ, 256, 0, stream>>>(output_s, output_t, target, tweight, ws);
    pass2_kernel<<<1, 64, 0, stream>>>(ws, enj, out);
}